// Round 4
// baseline (381.072 us; speedup 1.0000x reference)
//
#include <hip/hip_runtime.h>

#define PI_D 3.14159265358979323846

#define BATCH   64
#define LWAV    160000
#define NFFT    2048
#define HOP     512
#define NMELS   128
#define NFRAMES 313      // 1 + 160000/512
#define NCPLX   1024     // complex FFT size (real-pack)
#define PADW    1024     // NFFT/2

// PCEN chunked scan
#define NCH     16
#define CHLEN   20       // 15*20 + 13 = 313

// workspace layout (float offsets)
#define OFF_WIN  0        // 2048 window (natural order, read as float2)
#define OFF_TBL  2048     // float4[1024]: {kidx, wA, wB, 0} in NATURAL k order
#define OFF_MFIN 6144     // 64*16*128 chunk-local final EMA states
#define OFF_MEL  137216   // NFRAMES * BATCH * NMELS  (t-major mel buffer)

#define LROW 17           // padded row stride (floats) in transpose buffers
#define SW4(u) ((((u)&3)<<2)|((u)>>2))   // base-4 digit swap of 4-bit index
#define CMULC(xr, xi, cr, ci) { float _t = (xr); (xr) = _t*(cr) - (xi)*(ci); (xi) = _t*(ci) + (xi)*(cr); }

// 12 blocks: 0-7 window slices, 8-11 filterbank quarters (natural k order).
__global__ __launch_bounds__(256) void init_tables(float* __restrict__ ws) {
    __shared__ double fpts[130];
    const int tid = threadIdx.x;
    const int blk = blockIdx.x;
    if (blk < 8) {
        int i = blk * 256 + tid;
        double w = 0.5 - 0.5 * cos(2.0 * PI_D * (double)i / (double)NFFT);
        ws[OFF_WIN + i] = (float)w;
        return;
    }
    if (tid < 130) {
        double mlo = 2595.0 * log10(1.0 + 20.0 / 700.0);
        double mhi = 2595.0 * log10(1.0 + 16000.0 / 700.0);
        double m = mlo + (mhi - mlo) * (double)tid / 129.0;
        fpts[tid] = 700.0 * (pow(10.0, m / 2595.0) - 1.0);
    }
    __syncthreads();
    float4* tbl = (float4*)(ws + OFF_TBL);
    int k = (blk - 8) * 256 + tid;   // natural frequency bin 0..1023
    {
        double fhz = (double)k * 15.625;  // (SR/2)/1024 exact
        float wa = 0.f, wb = 0.f;
        int ka = 0, kb = 0;
        int kf = -1;
        for (int i = 0; i < 130; i++) kf += (fpts[i] <= fhz) ? 1 : 0;
        if (kf >= 0 && kf <= 127) {
            double down = (fhz - fpts[kf]) / (fpts[kf + 1] - fpts[kf]);
            double up   = (fpts[kf + 2] - fhz) / (fpts[kf + 2] - fpts[kf + 1]);
            double w = down < up ? down : up;
            if (w > 0.0) { wa = (float)w; ka = kf; }
        }
        int km = kf - 1;
        if (km >= 0 && km <= 127) {
            double down = (fhz - fpts[km]) / (fpts[km + 1] - fpts[km]);
            double up   = (fpts[km + 2] - fhz) / (fpts[km + 2] - fpts[km + 1]);
            double w = down < up ? down : up;
            if (w > 0.0) { wb = (float)w; kb = km; }
        }
        float4 v;
        v.x = __int_as_float(ka | (kb << 16));
        v.y = wa; v.z = wb; v.w = 0.f;
        tbl[k] = v;
    }
}

// 4-point DFT on slots (i0..i3): input index m in slot order, output p in slot order.
__device__ __forceinline__ void fft4s(float* yr, float* yi, int i0, int i1, int i2, int i3) {
    float t0r = yr[i0] + yr[i2], t0i = yi[i0] + yi[i2];
    float t1r = yr[i0] - yr[i2], t1i = yi[i0] - yi[i2];
    float t2r = yr[i1] + yr[i3], t2i = yi[i1] + yi[i3];
    float t3r = yr[i1] - yr[i3], t3i = yi[i1] - yi[i3];
    yr[i0] = t0r + t2r; yi[i0] = t0i + t2i;
    yr[i1] = t1r + t3i; yi[i1] = t1i - t3r;   // out1 = t1 - i*t3
    yr[i2] = t0r - t2r; yi[i2] = t0i - t2i;
    yr[i3] = t1r - t3i; yi[i3] = t1i + t3r;   // out3 = t1 + i*t3
}

// FFT-16 (natural input in slots 0..15). Output: slot s holds OUT[SW4(s)].
__device__ __forceinline__ void fft16(float* yr, float* yi) {
    fft4s(yr, yi, 0, 4, 8, 12);
    fft4s(yr, yi, 1, 5, 9, 13);
    fft4s(yr, yi, 2, 6, 10, 14);
    fft4s(yr, yi, 3, 7, 11, 15);
    // twiddle W16^{j*q} on slot j+4q
    CMULC(yr[5],  yi[5],   0.92387953f, -0.38268343f);  // W1
    CMULC(yr[9],  yi[9],   0.70710678f, -0.70710678f);  // W2
    CMULC(yr[13], yi[13],  0.38268343f, -0.92387953f);  // W3
    CMULC(yr[6],  yi[6],   0.70710678f, -0.70710678f);  // W2
    { float _t = yr[10]; yr[10] = yi[10]; yi[10] = -_t; } // W4 = -i
    CMULC(yr[14], yi[14], -0.70710678f, -0.70710678f);  // W6
    CMULC(yr[7],  yi[7],   0.38268343f, -0.92387953f);  // W3
    CMULC(yr[11], yi[11], -0.70710678f, -0.70710678f);  // W6
    CMULC(yr[15], yi[15], -0.92387953f,  0.38268343f);  // W9
    fft4s(yr, yi, 0, 1, 2, 3);
    fft4s(yr, yi, 4, 5, 6, 7);
    fft4s(yr, yi, 8, 9, 10, 11);
    fft4s(yr, yi, 12, 13, 14, 15);
}

// One WAVE per frame (block = 2 waves = 2 frames). Zero __syncthreads.
// 1024-pt FFT as 16(in-reg) x 4(in-reg) x 16(in-reg) with two wave-private
// LDS transposes; untwist via shfl; sparse mel scatter via LDS atomics.
__global__ __launch_bounds__(128) void fft_mel_kernel(const float* __restrict__ wav,
                                                      float* __restrict__ ws) {
    __shared__ float TAr[2][64 * LROW];
    __shared__ float TAi[2][64 * LROW];
    __shared__ float smel[2][NMELS];
    const int tid  = threadIdx.x;
    const int wv   = tid >> 6;
    const int lane = tid & 63;
    const int frame = blockIdx.x * 2 + wv;
    const int b = frame / NFRAMES;
    const int t = frame - b * NFRAMES;

    float yr[16], yi[16];
    const float* __restrict__ src = wav + (size_t)b * LWAV;
    const int base = t * HOP - PADW;    // even
    const float2* __restrict__ win2 = (const float2*)(ws + OFF_WIN);

    // ---- load + window: lane holds z[lane + 64c], c = 0..15 ----
    if (base >= 0 && base + NFFT <= LWAV) {
        const float2* __restrict__ s2 = (const float2*)(src + base);
#pragma unroll
        for (int c = 0; c < 16; c++) {
            int n = lane + 64 * c;
            float2 xv = s2[n];
            float2 wq = win2[n];
            yr[c] = xv.x * wq.x;
            yi[c] = xv.y * wq.y;
        }
    } else {
#pragma unroll
        for (int c = 0; c < 16; c++) {
            int n = lane + 64 * c;
            int i0 = base + 2 * n, i1 = i0 + 1;
            i0 = i0 < 0 ? -i0 : i0; i0 = i0 >= LWAV ? 2 * LWAV - 2 - i0 : i0;
            i1 = i1 < 0 ? -i1 : i1; i1 = i1 >= LWAV ? 2 * LWAV - 2 - i1 : i1;
            float2 wq = win2[n];
            yr[c] = src[i0] * wq.x;
            yi[c] = src[i1] * wq.y;
        }
    }
    smel[wv][lane] = 0.f;
    smel[wv][lane + 64] = 0.f;

    // ---- S1: FFT-16 over c (slot s = Y[SW4(s)]) ----
    fft16(yr, yi);

    // ---- T1: Y[u] *= W_1024^{lane*u} ----
    {
        float wr_, wi_;
        __sincosf(-6.13592315e-3f * (float)lane, &wi_, &wr_);  // sin, cos
        float cr = wr_, ci = wi_;   // cur = w^1
#pragma unroll
        for (int u = 1; u < 16; u++) {
            CMULC(yr[SW4(u)], yi[SW4(u)], cr, ci);
            if (u < 15) { CMULC(cr, ci, wr_, wi_); }
        }
    }

    // ---- X1: transpose (row = lane, col = u) -> read (b,m) from row a+16b ----
    float* __restrict__ tr = TAr[wv];
    float* __restrict__ ti = TAi[wv];
    {
        const int wbase = lane * LROW;
#pragma unroll
        for (int u = 0; u < 16; u++) { tr[wbase + u] = yr[SW4(u)]; ti[wbase + u] = yi[SW4(u)]; }
    }
    __builtin_amdgcn_wave_barrier();
    asm volatile("" ::: "memory");
    const int a = lane & 15, g = lane >> 4;
    {
        const int rbase = a * LROW + 4 * g;
#pragma unroll
        for (int bq = 0; bq < 4; bq++)
#pragma unroll
            for (int m = 0; m < 4; m++) {
                int idx = rbase + bq * (16 * LROW) + m;
                yr[4 * bq + m] = tr[idx];
                yi[4 * bq + m] = ti[idx];
            }
    }
    __builtin_amdgcn_wave_barrier();
    asm volatile("" ::: "memory");

    // ---- S2: FFT-4 over b (slot m+4s = G_s[u=4g+m]) ----
#pragma unroll
    for (int m = 0; m < 4; m++) fft4s(yr, yi, m, 4 + m, 8 + m, 12 + m);

    // ---- T2: *= W_64^{a*s} ----
    {
        float w1r, w1i;
        __sincosf(-9.81747704e-2f * (float)a, &w1i, &w1r);
        float w2r = w1r * w1r - w1i * w1i, w2i = 2.f * w1r * w1i;
        float w3r = w1r * w2r - w1i * w2i, w3i = w1r * w2i + w1i * w2r;
#pragma unroll
        for (int m = 0; m < 4; m++) {
            CMULC(yr[4 + m],  yi[4 + m],  w1r, w1i);
            CMULC(yr[8 + m],  yi[8 + m],  w2r, w2i);
            CMULC(yr[12 + m], yi[12 + m], w3r, w3i);
        }
    }

    // ---- X2: transpose (row = 16s+4g+m, col = a) -> read own row = lane ----
    {
        const int a2 = 68 * g + a;
#pragma unroll
        for (int s = 0; s < 4; s++)
#pragma unroll
            for (int m = 0; m < 4; m++) {
                int idx = a2 + LROW * (16 * s + m);
                tr[idx] = yr[4 * s + m];
                ti[idx] = yi[4 * s + m];
            }
    }
    __builtin_amdgcn_wave_barrier();
    asm volatile("" ::: "memory");
    {
        const int rb2 = lane * LROW;
#pragma unroll
        for (int aa = 0; aa < 16; aa++) { yr[aa] = tr[rb2 + aa]; yi[aa] = ti[rb2 + aa]; }
    }
    __builtin_amdgcn_wave_barrier();
    asm volatile("" ::: "memory");

    // ---- S3: FFT-16 over a. Slot s holds X[lane + 64*SW4(s)] ----
    fft16(yr, yi);

    // ---- untwist (real-pack) + power + mel scatter ----
    {
        const int pl = (64 - lane) & 63;            // partner lane
        float er, ei;
        __sincosf(-3.06796158e-3f * (float)lane, &ei, &er);   // e^{-i pi lane/1024}
        const float4* __restrict__ tbl = (const float4*)(ws + OFF_TBL);
        float prevR = __shfl(yr[0], pl, 64), prevI = __shfl(yi[0], pl, 64); // slot SW4(0)
#pragma unroll
        for (int tt = 0; tt < 16; tt++) {
            const int sl = SW4(15 - tt);
            float curR = __shfl(yr[sl], pl, 64), curI = __shfl(yi[sl], pl, 64);
            float pr = (lane == 0) ? prevR : curR;
            float pi = (lane == 0) ? prevI : curI;
            const int ms = SW4(tt);
            float zr = yr[ms], zi = yi[ms];
            float Ar = 0.5f * (zr + pr), Ai = 0.5f * (zi - pi);
            float Or = 0.5f * (zi + pi), Oi = -0.5f * (zr - pr);
            float Xr = Ar + er * Or - ei * Oi;
            float Xi = Ai + er * Oi + ei * Or;
            float pw = Xr * Xr + Xi * Xi;
            float4 tb = tbl[lane + 64 * tt];
            int kk = __float_as_int(tb.x);
            atomicAdd(&smel[wv][kk & 0xffff], pw * tb.y);
            atomicAdd(&smel[wv][kk >> 16],    pw * tb.z);
            prevR = curR; prevI = curI;
            CMULC(er, ei, 0.98078528f, -0.19509032f);   // *= e^{-i pi/16}
        }
    }
    __builtin_amdgcn_wave_barrier();
    asm volatile("" ::: "memory");
    float* __restrict__ mout = ws + OFF_MEL + (size_t)t * (BATCH * NMELS) + b * NMELS;
    mout[lane] = smel[wv][lane];
    mout[lane + 64] = smel[wv][lane + 64];
}

// Phase 1: per-(b,chunk) local EMA with zero init; write final state.
__global__ __launch_bounds__(128) void pcen_scan1(float* __restrict__ ws) {
    const int bx = blockIdx.x;
    const int b = bx >> 4, c = bx & 15;
    const int tid = threadIdx.x;
    const int t0 = c * CHLEN;
    const int len = (c == NCH - 1) ? (NFRAMES - t0) : CHLEN;
    const float* __restrict__ mel = ws + OFF_MEL + b * NMELS + tid;
    float m = 0.f;
#pragma unroll 5
    for (int t = 0; t < len; t++) {
        float x = mel[(size_t)(t0 + t) * (BATCH * NMELS)];
        m = fmaf(0.975f, m, 0.025f * x);
    }
    ws[OFF_MFIN + (b * NCH + c) * NMELS + tid] = m;
}

// Phase 2: fold incoming state, recompute chunk, emit transposed output.
__global__ __launch_bounds__(128) void pcen_scan2(const float* __restrict__ ws,
                                                  float* __restrict__ out) {
    __shared__ float tile[CHLEN * 129];
    const int bx = blockIdx.x;
    const int b = bx >> 4, c = bx & 15;
    const int tid = threadIdx.x;
    const int t0 = c * CHLEN;
    const int len = (c == NCH - 1) ? (NFRAMES - t0) : CHLEN;
    double Apd = 1.0;
    for (int i = 0; i < CHLEN; i++) Apd *= 0.975;
    const float Ap = (float)Apd;
    float m = 0.f;
    const float* __restrict__ mfin = ws + OFF_MFIN + b * NCH * NMELS + tid;
    for (int cc = 0; cc < c; cc++) m = fmaf(Ap, m, mfin[cc * NMELS]);
    const float* __restrict__ mel = ws + OFF_MEL + b * NMELS + tid;
    for (int t = 0; t < len; t++) {
        float x = mel[(size_t)(t0 + t) * (BATCH * NMELS)];
        m = fmaf(0.975f, m, 0.025f * x);
        float d = 1e-6f + m;
        float pd = exp2f(-0.98f * __log2f(d));
        float p = sqrtf(fmaf(x, pd, 2.0f)) - 1.41421356237f;
        tile[t * 129 + tid] = p;
    }
    __syncthreads();
    for (int idx = tid; idx < len * 128; idx += 128) {
        int row = idx / len, col = idx - row * len;
        out[(size_t)(b * NMELS + row) * NFRAMES + t0 + col] = tile[col * 129 + row];
    }
}

extern "C" void kernel_launch(void* const* d_in, const int* in_sizes, int n_in,
                              void* d_out, int out_size, void* d_ws, size_t ws_size,
                              hipStream_t stream) {
    const float* wav = (const float*)d_in[0];
    float* out = (float*)d_out;
    float* ws = (float*)d_ws;
    init_tables<<<12, 256, 0, stream>>>(ws);
    fft_mel_kernel<<<(BATCH * NFRAMES) / 2, 128, 0, stream>>>(wav, ws);
    pcen_scan1<<<BATCH * NCH, 128, 0, stream>>>(ws);
    pcen_scan2<<<BATCH * NCH, 128, 0, stream>>>(ws, out);
}

// Round 5
// 153.987 us; speedup vs baseline: 2.4747x; 2.4747x over previous
//
#include <hip/hip_runtime.h>

#define PI_D 3.14159265358979323846

#define BATCH   64
#define LWAV    160000
#define NFFT    2048
#define HOP     512
#define NMELS   128
#define NFRAMES 313      // 1 + 160000/512
#define NCPLX   1024     // complex FFT size (real-pack)
#define PADW    1024     // NFFT/2

// PCEN chunked scan
#define NCH     16
#define CHLEN   20       // 15*20 + 13 = 313

// workspace layout (float offsets)
#define OFF_WIN  0        // 2048 window (natural order, read as float2)
#define OFF_LEN  2048     // 128 ints: CSR length per mel
#define OFF_KK   2176     // int[65][128]: bin index, entry-major (prefetch-safe pad)
#define OFF_WW   10496    // float[65][128]: weight
#define OFF_MFIN 18816    // 64*16*128 chunk-local final EMA states
#define OFF_MEL  149888   // NFRAMES * BATCH * NMELS (t-major mel buffer)

#define LROW 17           // padded row stride (floats) in transpose buffers
#define TSTR (64 * LROW)  // 1088 floats per wave region
#define SW4(u) ((((u)&3)<<2)|((u)>>2))   // base-4 digit swap of 4-bit index
#define CMULC(xr, xi, cr, ci) { float _t = (xr); (xr) = _t*(cr) - (xi)*(ci); (xi) = _t*(ci) + (xi)*(cr); }

__device__ __forceinline__ double melpt(int i) {
    double mlo = 2595.0 * log10(1.0 + 20.0 / 700.0);
    double mhi = 2595.0 * log10(1.0 + 16000.0 / 700.0);
    double m = mlo + (mhi - mlo) * (double)i / 129.0;
    return 700.0 * (pow(10.0, m / 2595.0) - 1.0);
}

// 9 blocks: 0-7 window slices, 8 = per-mel CSR build.
__global__ __launch_bounds__(256) void init_tables(float* __restrict__ ws) {
    const int tid = threadIdx.x;
    const int blk = blockIdx.x;
    if (blk < 8) {
        int i = blk * 256 + tid;
        double w = 0.5 - 0.5 * cos(2.0 * PI_D * (double)i / (double)NFFT);
        ws[OFF_WIN + i] = (float)w;
        return;
    }
    if (tid >= NMELS) return;
    const int m = tid;
    double fp0 = melpt(m), fp1 = melpt(m + 1), fp2 = melpt(m + 2);
    int* kk = (int*)(ws + OFF_KK);
    float* wwt = ws + OFF_WW;
    int k0 = (int)(fp0 / 15.625); if (k0 < 1) k0 = 1;
    int k1 = (int)(fp2 / 15.625) + 1; if (k1 > 1023) k1 = 1023;
    int cnt = 0;
    for (int k = k0; k <= k1; k++) {
        double f = (double)k * 15.625;
        double down = (f - fp0) / (fp1 - fp0);
        double up   = (fp2 - f) / (fp2 - fp1);
        double w = down < up ? down : up;
        if (w > 0.0 && cnt < 64) {
            kk[cnt * NMELS + m] = k;
            wwt[cnt * NMELS + m] = (float)w;
            cnt++;
        }
    }
    ((int*)(ws + OFF_LEN))[m] = cnt;
    for (int e = cnt; e < 65; e++) {
        kk[e * NMELS + m] = 0;
        wwt[e * NMELS + m] = 0.f;
    }
}

// 4-point DFT on slots (i0..i3).
__device__ __forceinline__ void fft4s(float* yr, float* yi, int i0, int i1, int i2, int i3) {
    float t0r = yr[i0] + yr[i2], t0i = yi[i0] + yi[i2];
    float t1r = yr[i0] - yr[i2], t1i = yi[i0] - yi[i2];
    float t2r = yr[i1] + yr[i3], t2i = yi[i1] + yi[i3];
    float t3r = yr[i1] - yr[i3], t3i = yi[i1] - yi[i3];
    yr[i0] = t0r + t2r; yi[i0] = t0i + t2i;
    yr[i1] = t1r + t3i; yi[i1] = t1i - t3r;   // out1 = t1 - i*t3
    yr[i2] = t0r - t2r; yi[i2] = t0i - t2i;
    yr[i3] = t1r - t3i; yi[i3] = t1i + t3r;   // out3 = t1 + i*t3
}

// FFT-16 (natural input in slots 0..15). Output: slot s holds OUT[SW4(s)].
__device__ __forceinline__ void fft16(float* yr, float* yi) {
    fft4s(yr, yi, 0, 4, 8, 12);
    fft4s(yr, yi, 1, 5, 9, 13);
    fft4s(yr, yi, 2, 6, 10, 14);
    fft4s(yr, yi, 3, 7, 11, 15);
    CMULC(yr[5],  yi[5],   0.92387953f, -0.38268343f);  // W1
    CMULC(yr[9],  yi[9],   0.70710678f, -0.70710678f);  // W2
    CMULC(yr[13], yi[13],  0.38268343f, -0.92387953f);  // W3
    CMULC(yr[6],  yi[6],   0.70710678f, -0.70710678f);  // W2
    { float _t = yr[10]; yr[10] = yi[10]; yi[10] = -_t; } // W4 = -i
    CMULC(yr[14], yi[14], -0.70710678f, -0.70710678f);  // W6
    CMULC(yr[7],  yi[7],   0.38268343f, -0.92387953f);  // W3
    CMULC(yr[11], yi[11], -0.70710678f, -0.70710678f);  // W6
    CMULC(yr[15], yi[15], -0.92387953f,  0.38268343f);  // W9
    fft4s(yr, yi, 0, 1, 2, 3);
    fft4s(yr, yi, 4, 5, 6, 7);
    fft4s(yr, yi, 8, 9, 10, 11);
    fft4s(yr, yi, 12, 13, 14, 15);
}

// Block = 4 waves = 4 frames. Per wave: 1024-pt FFT (16x4x16, two wave-private
// LDS transposes, zero block barriers) -> untwist -> power into own (dead)
// transpose buffer. Then ONE __syncthreads -> batched no-atomic mel gather
// (thread (m,h) does mel m for 2 frames via precomputed CSR, prefetched).
__global__ __launch_bounds__(256) void fft_mel_kernel(const float* __restrict__ wav,
                                                      float* __restrict__ ws) {
    __shared__ float TAr[4][TSTR];
    __shared__ float TAi[4][TSTR];
    const int tid  = threadIdx.x;
    const int wv   = tid >> 6;
    const int lane = tid & 63;
    const int frame = blockIdx.x * 4 + wv;
    const int b = frame / NFRAMES;
    const int t = frame - b * NFRAMES;

    float yr[16], yi[16];
    const float* __restrict__ src = wav + (size_t)b * LWAV;
    const int base = t * HOP - PADW;    // even
    const float2* __restrict__ win2 = (const float2*)(ws + OFF_WIN);

    // ---- load + window: lane holds z[lane + 64c], c = 0..15 ----
    if (base >= 0 && base + NFFT <= LWAV) {
        const float2* __restrict__ s2 = (const float2*)(src + base);
#pragma unroll
        for (int c = 0; c < 16; c++) {
            int n = lane + 64 * c;
            float2 xv = s2[n];
            float2 wq = win2[n];
            yr[c] = xv.x * wq.x;
            yi[c] = xv.y * wq.y;
        }
    } else {
#pragma unroll
        for (int c = 0; c < 16; c++) {
            int n = lane + 64 * c;
            int i0 = base + 2 * n, i1 = i0 + 1;
            i0 = i0 < 0 ? -i0 : i0; i0 = i0 >= LWAV ? 2 * LWAV - 2 - i0 : i0;
            i1 = i1 < 0 ? -i1 : i1; i1 = i1 >= LWAV ? 2 * LWAV - 2 - i1 : i1;
            float2 wq = win2[n];
            yr[c] = src[i0] * wq.x;
            yi[c] = src[i1] * wq.y;
        }
    }

    // ---- S1: FFT-16 over c ----
    fft16(yr, yi);

    // ---- T1: Y[u] *= W_1024^{lane*u} ----
    {
        float wr_, wi_;
        __sincosf(-6.13592315e-3f * (float)lane, &wi_, &wr_);
        float cr = wr_, ci = wi_;
#pragma unroll
        for (int u = 1; u < 16; u++) {
            CMULC(yr[SW4(u)], yi[SW4(u)], cr, ci);
            if (u < 15) { CMULC(cr, ci, wr_, wi_); }
        }
    }

    // ---- X1: transpose ----
    float* __restrict__ tr = TAr[wv];
    float* __restrict__ ti = TAi[wv];
    {
        const int wbase = lane * LROW;
#pragma unroll
        for (int u = 0; u < 16; u++) { tr[wbase + u] = yr[SW4(u)]; ti[wbase + u] = yi[SW4(u)]; }
    }
    __builtin_amdgcn_wave_barrier();
    asm volatile("" ::: "memory");
    const int a = lane & 15, g = lane >> 4;
    {
        const int rbase = a * LROW + 4 * g;
#pragma unroll
        for (int bq = 0; bq < 4; bq++)
#pragma unroll
            for (int m = 0; m < 4; m++) {
                int idx = rbase + bq * (16 * LROW) + m;
                yr[4 * bq + m] = tr[idx];
                yi[4 * bq + m] = ti[idx];
            }
    }
    __builtin_amdgcn_wave_barrier();
    asm volatile("" ::: "memory");

    // ---- S2: FFT-4 over b ----
#pragma unroll
    for (int m = 0; m < 4; m++) fft4s(yr, yi, m, 4 + m, 8 + m, 12 + m);

    // ---- T2: *= W_64^{a*s} ----
    {
        float w1r, w1i;
        __sincosf(-9.81747704e-2f * (float)a, &w1i, &w1r);
        float w2r = w1r * w1r - w1i * w1i, w2i = 2.f * w1r * w1i;
        float w3r = w1r * w2r - w1i * w2i, w3i = w1r * w2i + w1i * w2r;
#pragma unroll
        for (int m = 0; m < 4; m++) {
            CMULC(yr[4 + m],  yi[4 + m],  w1r, w1i);
            CMULC(yr[8 + m],  yi[8 + m],  w2r, w2i);
            CMULC(yr[12 + m], yi[12 + m], w3r, w3i);
        }
    }

    // ---- X2: transpose ----
    {
        const int a2 = 68 * g + a;
#pragma unroll
        for (int s = 0; s < 4; s++)
#pragma unroll
            for (int m = 0; m < 4; m++) {
                int idx = a2 + LROW * (16 * s + m);
                tr[idx] = yr[4 * s + m];
                ti[idx] = yi[4 * s + m];
            }
    }
    __builtin_amdgcn_wave_barrier();
    asm volatile("" ::: "memory");
    {
        const int rb2 = lane * LROW;
#pragma unroll
        for (int aa = 0; aa < 16; aa++) { yr[aa] = tr[rb2 + aa]; yi[aa] = ti[rb2 + aa]; }
    }
    __builtin_amdgcn_wave_barrier();
    asm volatile("" ::: "memory");

    // ---- S3: FFT-16 over a. Slot s holds X[lane + 64*SW4(s)] ----
    fft16(yr, yi);

    // ---- untwist + power -> own transpose buffer (dead), bank = lane: conflict-free ----
    {
        const int pl = (64 - lane) & 63;            // partner lane
        float er, ei;
        __sincosf(-3.06796158e-3f * (float)lane, &ei, &er);   // e^{-i pi lane/1024}
        float prevR = __shfl(yr[0], pl, 64), prevI = __shfl(yi[0], pl, 64);
#pragma unroll
        for (int tt = 0; tt < 16; tt++) {
            const int sl = SW4(15 - tt);
            float curR = __shfl(yr[sl], pl, 64), curI = __shfl(yi[sl], pl, 64);
            float pr = (lane == 0) ? prevR : curR;
            float pi = (lane == 0) ? prevI : curI;
            const int ms = SW4(tt);
            float zr = yr[ms], zi = yi[ms];
            float Ar = 0.5f * (zr + pr), Ai = 0.5f * (zi - pi);
            float Or = 0.5f * (zi + pi), Oi = -0.5f * (zr - pr);
            float Xr = Ar + er * Or - ei * Oi;
            float Xi = Ai + er * Oi + ei * Or;
            tr[lane + 64 * tt] = Xr * Xr + Xi * Xi;   // power[k], k = lane+64tt
            prevR = curR; prevI = curI;
            CMULC(er, ei, 0.98078528f, -0.19509032f);   // *= e^{-i pi/16}
        }
    }
    __syncthreads();

    // ---- batched mel gather: thread (m, h) -> mel m of frames 2h, 2h+1 ----
    {
        const int m = tid & 127;
        const int h = tid >> 7;
        const int L = ((const int*)(ws + OFF_LEN))[m];
        const int* __restrict__ kk = (const int*)(ws + OFF_KK);
        const float* __restrict__ wwt = ws + OFF_WW;
        const float* __restrict__ P0 = TAr[2 * h];
        const float* __restrict__ P1 = TAr[2 * h + 1];
        float a0 = 0.f, a1 = 0.f;
        int k = kk[m];
        float w = wwt[m];
        for (int e = 0; e < L; e++) {
            int k2 = kk[(e + 1) * NMELS + m];        // prefetch (pad row 65)
            float w2 = wwt[(e + 1) * NMELS + m];
            a0 = fmaf(w, P0[k], a0);
            a1 = fmaf(w, P1[k], a1);
            k = k2; w = w2;
        }
        const int fr0 = blockIdx.x * 4 + 2 * h;
        const int b0 = fr0 / NFRAMES, t0 = fr0 - b0 * NFRAMES;
        const int fr1 = fr0 + 1;
        const int b1 = fr1 / NFRAMES, t1 = fr1 - b1 * NFRAMES;
        ws[OFF_MEL + (size_t)t0 * (BATCH * NMELS) + b0 * NMELS + m] = a0;
        ws[OFF_MEL + (size_t)t1 * (BATCH * NMELS) + b1 * NMELS + m] = a1;
    }
}

// Phase 1: per-(b,chunk) local EMA with zero init; write final state.
__global__ __launch_bounds__(128) void pcen_scan1(float* __restrict__ ws) {
    const int bx = blockIdx.x;
    const int b = bx >> 4, c = bx & 15;
    const int tid = threadIdx.x;
    const int t0 = c * CHLEN;
    const int len = (c == NCH - 1) ? (NFRAMES - t0) : CHLEN;
    const float* __restrict__ mel = ws + OFF_MEL + b * NMELS + tid;
    float m = 0.f;
#pragma unroll 5
    for (int t = 0; t < len; t++) {
        float x = mel[(size_t)(t0 + t) * (BATCH * NMELS)];
        m = fmaf(0.975f, m, 0.025f * x);
    }
    ws[OFF_MFIN + (b * NCH + c) * NMELS + tid] = m;
}

// Phase 2: fold incoming state, recompute chunk, emit transposed output.
__global__ __launch_bounds__(128) void pcen_scan2(const float* __restrict__ ws,
                                                  float* __restrict__ out) {
    __shared__ float tile[CHLEN * 129];
    const int bx = blockIdx.x;
    const int b = bx >> 4, c = bx & 15;
    const int tid = threadIdx.x;
    const int t0 = c * CHLEN;
    const int len = (c == NCH - 1) ? (NFRAMES - t0) : CHLEN;
    double Apd = 1.0;
    for (int i = 0; i < CHLEN; i++) Apd *= 0.975;
    const float Ap = (float)Apd;
    float m = 0.f;
    const float* __restrict__ mfin = ws + OFF_MFIN + b * NCH * NMELS + tid;
    for (int cc = 0; cc < c; cc++) m = fmaf(Ap, m, mfin[cc * NMELS]);
    const float* __restrict__ mel = ws + OFF_MEL + b * NMELS + tid;
    for (int t = 0; t < len; t++) {
        float x = mel[(size_t)(t0 + t) * (BATCH * NMELS)];
        m = fmaf(0.975f, m, 0.025f * x);
        float d = 1e-6f + m;
        float pd = exp2f(-0.98f * __log2f(d));
        float p = sqrtf(fmaf(x, pd, 2.0f)) - 1.41421356237f;
        tile[t * 129 + tid] = p;
    }
    __syncthreads();
    for (int idx = tid; idx < len * 128; idx += 128) {
        int row = idx / len, col = idx - row * len;
        out[(size_t)(b * NMELS + row) * NFRAMES + t0 + col] = tile[col * 129 + row];
    }
}

extern "C" void kernel_launch(void* const* d_in, const int* in_sizes, int n_in,
                              void* d_out, int out_size, void* d_ws, size_t ws_size,
                              hipStream_t stream) {
    const float* wav = (const float*)d_in[0];
    float* out = (float*)d_out;
    float* ws = (float*)d_ws;
    init_tables<<<9, 256, 0, stream>>>(ws);
    fft_mel_kernel<<<(BATCH * NFRAMES) / 4, 256, 0, stream>>>(wav, ws);
    pcen_scan1<<<BATCH * NCH, 128, 0, stream>>>(ws);
    pcen_scan2<<<BATCH * NCH, 128, 0, stream>>>(ws, out);
}